// Round 1
// baseline (20617.543 us; speedup 1.0000x reference)
//
#include <hip/hip_runtime.h>

#define HH 100
#define G4 400     // 4*H
#define LL 4096
#define NT 512

// LDS layout (floats): whh1[40000] | h1[100] | h2[100] | gates[400]
#define LDS_FLOATS (40000 + 100 + 100 + 400)

__device__ __forceinline__ float sigmoidf_(float x) {
    return 1.0f / (1.0f + __expf(-x));
}
__device__ __forceinline__ float tanhf_(float x) {
    // saturates correctly: x>>0 -> exp=inf -> 1; x<<0 -> exp=0 -> -1
    return 1.0f - 2.0f / (__expf(2.0f * x) + 1.0f);
}

__global__ __launch_bounds__(NT, 2)
void lstm_seq_kernel(const float* __restrict__ x_seq,
                     const float* __restrict__ Wih0,
                     const float* __restrict__ Whh0,
                     const float* __restrict__ bih0,
                     const float* __restrict__ bhh0,
                     const float* __restrict__ Wih1,
                     const float* __restrict__ Whh1,
                     const float* __restrict__ bih1,
                     const float* __restrict__ bhh1,
                     const float* __restrict__ Wlin,
                     const float* __restrict__ blin,
                     float* __restrict__ out)
{
    extern __shared__ float lds[];
    float* whh1_s  = lds;                 // [400*100]
    float* h1_s    = lds + 40000;         // [100]
    float* h2_s    = h1_s + HH;           // [100]
    float* gates_s = h2_s + HH;           // [400]

    const int tid = threadIdx.x;

    // ---- stage W_hh_l1 into LDS (coalesced float4) ----
    {
        const float4* src = reinterpret_cast<const float4*>(Whh1);
        float4*       dst = reinterpret_cast<float4*>(whh1_s);
        for (int i = tid; i < 10000; i += NT) dst[i] = src[i];
    }
    if (tid < HH) { h1_s[tid] = 0.0f; h2_s[tid] = 0.0f; }

    // ---- per-thread register weights ----
    float wA[HH];   // W_hh_l0 row `tid`   (layer-0 recurrent)
    float wB[HH];   // W_ih_l1 row `tid`   (layer-1 input)
    float bA = 0.0f, bB = 0.0f, wx = 0.0f;
    if (tid < G4) {
        const float4* a4 = reinterpret_cast<const float4*>(Whh0) + tid * 25;
        const float4* b4 = reinterpret_cast<const float4*>(Wih1) + tid * 25;
        #pragma unroll
        for (int j = 0; j < 25; ++j) {
            float4 v = a4[j];
            wA[4*j+0] = v.x; wA[4*j+1] = v.y; wA[4*j+2] = v.z; wA[4*j+3] = v.w;
            float4 u = b4[j];
            wB[4*j+0] = u.x; wB[4*j+1] = u.y; wB[4*j+2] = u.z; wB[4*j+3] = u.w;
        }
        bA = bih0[tid] + bhh0[tid];
        bB = bih1[tid] + bhh1[tid];
        wx = Wih0[tid];
    }
    const float wl = (tid < HH) ? Wlin[tid] : 0.0f;
    float c0 = 0.0f, c1 = 0.0f;

    __syncthreads();

    for (int t = 0; t < LL; ++t) {
        const float xt = x_seq[t];

        // ---- Phase A: layer-0 gates  (reads h1 from step t-1) ----
        if (tid < G4) {
            float a0 = 0.f, a1 = 0.f, a2 = 0.f, a3 = 0.f;
            const float4* h4 = reinterpret_cast<const float4*>(h1_s);
            #pragma unroll
            for (int j = 0; j < 25; ++j) {
                float4 h = h4[j];
                a0 = fmaf(wA[4*j+0], h.x, a0);
                a1 = fmaf(wA[4*j+1], h.y, a1);
                a2 = fmaf(wA[4*j+2], h.z, a2);
                a3 = fmaf(wA[4*j+3], h.w, a3);
            }
            gates_s[tid] = (a0 + a1) + (a2 + a3) + bA + wx * xt;
        }
        __syncthreads();

        // ---- Gating A -> h1_new ----
        if (tid < HH) {
            float gi = gates_s[tid];
            float gf = gates_s[tid + HH];
            float gg = gates_s[tid + 2*HH];
            float go = gates_s[tid + 3*HH];
            c0 = sigmoidf_(gf) * c0 + sigmoidf_(gi) * tanhf_(gg);
            h1_s[tid] = sigmoidf_(go) * tanhf_(c0);
        }
        __syncthreads();

        // ---- Phase B: layer-1 gates (Wih1 . h1_new  +  Whh1 . h2_old) ----
        if (tid < G4) {
            float a0 = 0.f, a1 = 0.f, a2 = 0.f, a3 = 0.f;
            const float4* h4 = reinterpret_cast<const float4*>(h1_s);
            const float4* g4 = reinterpret_cast<const float4*>(h2_s);
            const float4* w4 = reinterpret_cast<const float4*>(whh1_s) + tid * 25;
            #pragma unroll
            for (int j = 0; j < 25; ++j) {
                float4 h = h4[j];
                a0 = fmaf(wB[4*j+0], h.x, a0);
                a1 = fmaf(wB[4*j+1], h.y, a1);
                a2 = fmaf(wB[4*j+2], h.z, a2);
                a3 = fmaf(wB[4*j+3], h.w, a3);
            }
            #pragma unroll
            for (int j = 0; j < 25; ++j) {
                float4 w = w4[j];
                float4 h = g4[j];
                a0 = fmaf(w.x, h.x, a0);
                a1 = fmaf(w.y, h.y, a1);
                a2 = fmaf(w.z, h.z, a2);
                a3 = fmaf(w.w, h.w, a3);
            }
            gates_s[tid] = (a0 + a1) + (a2 + a3) + bB;
        }
        __syncthreads();

        // ---- Gating B -> h2_new ----
        if (tid < HH) {
            float gi = gates_s[tid];
            float gf = gates_s[tid + HH];
            float gg = gates_s[tid + 2*HH];
            float go = gates_s[tid + 3*HH];
            c1 = sigmoidf_(gf) * c1 + sigmoidf_(gi) * tanhf_(gg);
            h2_s[tid] = sigmoidf_(go) * tanhf_(c1);
        }
        __syncthreads();
    }

    // ---- final projection: out = h2 . Wlin + blin ----
    if (tid < HH) gates_s[tid] = wl * h2_s[tid];
    __syncthreads();
    if (tid == 0) {
        float s = 0.0f;
        for (int k = 0; k < HH; ++k) s += gates_s[k];
        out[0] = s + blin[0];
    }
}

extern "C" void kernel_launch(void* const* d_in, const int* in_sizes, int n_in,
                              void* d_out, int out_size, void* d_ws, size_t ws_size,
                              hipStream_t stream) {
    (void)in_sizes; (void)n_in; (void)out_size; (void)d_ws; (void)ws_size;

    const float* x_seq = (const float*)d_in[0];
    const float* Wih0  = (const float*)d_in[1];
    const float* Whh0  = (const float*)d_in[2];
    const float* bih0  = (const float*)d_in[3];
    const float* bhh0  = (const float*)d_in[4];
    const float* Wih1  = (const float*)d_in[5];
    const float* Whh1  = (const float*)d_in[6];
    const float* bih1  = (const float*)d_in[7];
    const float* bhh1  = (const float*)d_in[8];
    const float* Wlin  = (const float*)d_in[9];
    const float* blin  = (const float*)d_in[10];
    float* out = (float*)d_out;

    static bool attr_set = false;
    if (!attr_set) {
        // allow >64KB dynamic LDS if the runtime requires opt-in (no-op otherwise)
        hipFuncSetAttribute((const void*)lstm_seq_kernel,
                            hipFuncAttributeMaxDynamicSharedMemorySize,
                            LDS_FLOATS * (int)sizeof(float));
        attr_set = true;
    }

    hipLaunchKernelGGL(lstm_seq_kernel, dim3(1), dim3(NT),
                       LDS_FLOATS * sizeof(float), stream,
                       x_seq, Wih0, Whh0, bih0, bhh0,
                       Wih1, Whh1, bih1, bhh1, Wlin, blin, out);
}